// Round 9
// baseline (701.518 us; speedup 1.0000x reference)
//
#include <hip/hip_runtime.h>
#include <hip/hip_bf16.h>
#include <math.h>

#define B_   8
#define S_   2048
#define T_   (B_*S_)      // 16384 tokens
#define FIN  256
#define E_   512
#define H_   8
#define D_   64
#define FFN_ 2048
#define NC_  1000
#define NW_  8

typedef __attribute__((ext_vector_type(8))) short short8;
typedef __attribute__((ext_vector_type(4))) short short4v;
typedef __attribute__((ext_vector_type(4))) float f32x4;
typedef __attribute__((ext_vector_type(2))) unsigned int uint2v;
typedef __attribute__((ext_vector_type(4))) unsigned int uint4v;

__device__ __forceinline__ unsigned short f2bf(float f) {
    __hip_bfloat16 h = __float2bfloat16(f);
    return __builtin_bit_cast(unsigned short, h);
}
__device__ __forceinline__ float bf2f(unsigned short u) {
    return __builtin_bit_cast(float, (unsigned int)u << 16);
}

// packed f32x2 -> bf16x2 (single VALU instr; no builtin on gfx950)
__device__ __forceinline__ unsigned cvtpk_bf16(float lo, float hi) {
    unsigned r;
    asm("v_cvt_pk_bf16_f32 %0, %1, %2" : "=v"(r) : "v"(lo), "v"(hi));
    return r;
}

#if defined(__has_builtin)
#if __has_builtin(__builtin_amdgcn_permlane32_swap) && __has_builtin(__builtin_amdgcn_permlane16_swap)
#define HAVE_PLSWAP 1
#endif
#endif

// exchange lane-bit 5 (xor32) with the a/b register bit
__device__ __forceinline__ void lswap32(unsigned &a, unsigned &b) {
#if defined(HAVE_PLSWAP)
    uint2v t = __builtin_amdgcn_permlane32_swap(a, b, false, false);
    a = t[0]; b = t[1];
#else
    unsigned as = (unsigned)__shfl_xor((int)a, 32);
    unsigned bs = (unsigned)__shfl_xor((int)b, 32);
    bool hi = (threadIdx.x & 32) != 0;
    unsigned na = hi ? bs : a;
    unsigned nb = hi ? b  : as;
    a = na; b = nb;
#endif
}
// exchange lane-bit 4 (xor16) with the a/b register bit
__device__ __forceinline__ void lswap16(unsigned &a, unsigned &b) {
#if defined(HAVE_PLSWAP)
    uint2v t = __builtin_amdgcn_permlane16_swap(a, b, false, false);
    a = t[0]; b = t[1];
#else
    unsigned as = (unsigned)__shfl_xor((int)a, 16);
    unsigned bs = (unsigned)__shfl_xor((int)b, 16);
    bool hi = (threadIdx.x & 16) != 0;
    unsigned na = hi ? bs : a;
    unsigned nb = hi ? b  : as;
    a = na; b = nb;
#endif
}

// async global->LDS, 16B per lane; LDS dest = wave-uniform base + lane*16
__device__ __forceinline__ void gld16(void* l, const void* g) {
    __builtin_amdgcn_global_load_lds(
        (const __attribute__((address_space(1))) unsigned int*)g,
        (__attribute__((address_space(3))) unsigned int*)l,
        16, 0, 0);
}

#if defined(__has_builtin)
#if __has_builtin(__builtin_amdgcn_mfma_f32_16x16x16bf16_1k)
#define HAVE_MFMA16 1
#endif
#endif

// K=16 bf16 MFMA: A[m=lane&15][k=quad*4+j]; B[n=lane&15][k=quad*4+j];
// C col=lane&15(n), row=quad*4+r(m)
__device__ __forceinline__ f32x4 mfma16(short4v a, short4v b, f32x4 c) {
#ifdef HAVE_MFMA16
    return __builtin_amdgcn_mfma_f32_16x16x16bf16_1k(a, b, c, 0, 0, 0);
#else
    short8 a8 = {a[0], a[1], a[2], a[3], 0, 0, 0, 0};
    short8 b8 = {b[0], b[1], b[2], b[3], 0, 0, 0, 0};
    return __builtin_amdgcn_mfma_f32_16x16x32_bf16(a8, b8, c, 0, 0, 0);
#endif
}

// ---------------------------------------------------------------------------
// fp32 -> bf16 bulk conversion: x | Wi | W2(2l) | W1(2l).
// float4 prefix: 1048576 | 1081344 | 1605632 | 1613824 -> 6304 blocks
// ---------------------------------------------------------------------------
__global__ __launch_bounds__(256)
void cvt_all(const float* __restrict__ x,  const float* __restrict__ Wi,
             const float* __restrict__ W2, const float* __restrict__ W1,
             unsigned short* xb, unsigned short* Wib,
             unsigned short* W2b, unsigned short* W1b)
{
    int g = blockIdx.x*256 + threadIdx.x;
    const float* s; unsigned short* d; int o;
    if      (g < 1048576) { s = x;  d = xb;  o = g; }
    else if (g < 1081344) { s = Wi; d = Wib; o = g - 1048576; }
    else if (g < 1605632) { s = W2; d = W2b; o = g - 1081344; }
    else                  { s = W1; d = W1b; o = g - 1605632; }
    float4 vv = ((const float4*)s)[o];
    ushort4 u;
    u.x = f2bf(vv.x); u.y = f2bf(vv.y); u.z = f2bf(vv.z); u.w = f2bf(vv.w);
    ((ushort4*)d)[o] = u;
}

// ---------------------------------------------------------------------------
// Weff[which][l][f][w] = scale * sum_e W[l][f][e] * Wproj[l][e][w]  -> bf16
// ---------------------------------------------------------------------------
__global__ __launch_bounds__(64)
void weff_kernel(const float* __restrict__ Wq, const float* __restrict__ Wk,
                 const float* __restrict__ Wv, const float* __restrict__ Wproj,
                 unsigned short* __restrict__ Weff)
{
    const int f = blockIdx.x, l = blockIdx.y, which = blockIdx.z;
    const int lane = threadIdx.x;
    const float* W = (which == 0 ? Wq : which == 1 ? Wk : Wv)
                     + (size_t)l*E_*E_ + (size_t)f*E_;
    const float* P = Wproj + (size_t)l*E_*NW_;
    const int wv = lane & 7;
    float s = 0.f;
    for (int e = (lane >> 3)*64; e < (lane >> 3)*64 + 64; e++)
        s += W[e] * P[e*NW_ + wv];
    #pragma unroll
    for (int off = 8; off < 64; off <<= 1) s += __shfl_xor(s, off);
    const float scale = (which == 0) ? 0.18033688011112042f : 1.f;
    if (lane < 8)
        Weff[((size_t)(which*2 + l)*E_ + f)*NW_ + lane] = f2bf(s * scale);
}

// ---------------------------------------------------------------------------
// Gram matrix per head: G[l][h][w][w'] = sum_d Weff_q[h*64+d][w]*Weff_k[h*64+d][w']
// ---------------------------------------------------------------------------
__global__ __launch_bounds__(64)
void gram_kernel(const unsigned short* __restrict__ Weff, unsigned short* __restrict__ G)
{
    const int hh = blockIdx.x, l = blockIdx.y;
    const int lane = threadIdx.x;
    const int w = lane >> 3, wp = lane & 7;
    const unsigned short* Wq_e = Weff + (size_t)(0*2 + l)*E_*NW_ + (size_t)hh*64*NW_;
    const unsigned short* Wk_e = Weff + (size_t)(1*2 + l)*E_*NW_ + (size_t)hh*64*NW_;
    float s = 0.f;
    for (int d = 0; d < 64; d++)
        s += bf2f(Wq_e[d*NW_ + w]) * bf2f(Wk_e[d*NW_ + wp]);
    G[(size_t)(l*8 + hh)*64 + w*8 + wp] = f2bf(s);
}

// ---------------------------------------------------------------------------
// WoV[l][f][h*8+w] = sum_d Wo[l][f][h*64+d] * Weff_v[h*64+d][w]
// ---------------------------------------------------------------------------
__global__ __launch_bounds__(64)
void wov_kernel(const float* __restrict__ Wo, const unsigned short* __restrict__ Weff,
                unsigned short* __restrict__ WoV)
{
    const int f = blockIdx.x, l = blockIdx.y;
    const int lane = threadIdx.x;
    const int hh = lane >> 3, w = lane & 7;
    const float* wrow = Wo + (size_t)l*E_*E_ + (size_t)f*E_ + hh*64;
    const unsigned short* Wv_e = Weff + (size_t)(2*2 + l)*E_*NW_ + (size_t)hh*64*NW_;
    float s = 0.f;
    for (int d = 0; d < 64; d++)
        s += wrow[d] * bf2f(Wv_e[d*NW_ + w]);
    WoV[(size_t)(l*E_ + f)*64 + lane] = f2bf(s);
}

// ---------------------------------------------------------------------------
// Quantum-space encode: c8[t][8]=cos(h[..8]+theta); c8T[b][8][s] transposed;
// gk[b][h][s][8] = G_h . c8  (the pre-rotated K vectors).
// ---------------------------------------------------------------------------
__global__ __launch_bounds__(256)
void qc_small(const unsigned short* __restrict__ h, const float* __restrict__ theta,
              const unsigned short* __restrict__ G,
              unsigned short* __restrict__ c8, unsigned short* __restrict__ c8T,
              unsigned short* __restrict__ gkb)
{
    const int tid = threadIdx.x;
    const int t0 = blockIdx.x * 32;
    __shared__ float cs[32][8];
    __shared__ float Gs[512];
    {
        int tl = tid >> 3, wv2 = tid & 7;
        cs[tl][wv2] = cosf(bf2f(h[(size_t)(t0 + tl)*E_ + wv2]) + theta[wv2]);
        Gs[tid]       = bf2f(G[tid]);
        Gs[tid + 256] = bf2f(G[tid + 256]);
    }
    __syncthreads();
    const int tl = tid >> 3, hh = tid & 7;
    const int bb = (t0 + tl) >> 11, ss = (t0 + tl) & (S_ - 1);
    float c[8];
    #pragma unroll
    for (int i = 0; i < 8; i++) c[i] = cs[tl][i];
    unsigned short u[8] __attribute__((aligned(16)));
    #pragma unroll
    for (int w = 0; w < 8; w++) {
        float s = 0.f;
        #pragma unroll
        for (int wp = 0; wp < 8; wp++) s += Gs[hh*64 + w*8 + wp] * c[wp];
        u[w] = f2bf(s);
    }
    *(float4*)&gkb[((size_t)(bb*H_ + hh)*S_ + ss)*8] = *(float4*)u;
    if (tid < 32) {
        unsigned short v[8] __attribute__((aligned(16)));
        #pragma unroll
        for (int i = 0; i < 8; i++) v[i] = f2bf(cs[tid][i]);
        *(float4*)&c8[(size_t)(t0 + tid)*8] = *(float4*)v;
    } else if (tid < 40) {
        int w = tid - 32;
        unsigned short v[32] __attribute__((aligned(16)));
        #pragma unroll
        for (int s = 0; s < 32; s++) v[s] = f2bf(cs[s][w]);
        unsigned short* dst = c8T + ((size_t)(t0 >> 11)*8 + w)*S_ + (t0 & (S_ - 1));
        #pragma unroll
        for (int cq = 0; cq < 4; cq++) *(float4*)(dst + cq*8) = *(float4*)&v[cq*8];
    }
}

// ---------------------------------------------------------------------------
// All-bf16 MFMA GEMM: C = scale*(A[M][K] * W[N][K]^T). 128x128 tile, BK=32,
// double-buffered gld16. XCD swizzle. MODE 1: += bias + posenc.
// LDS-staged vectorized epilogue (float4 stores).
// NOTE: first instance per iteration absorbs harness poison traffic in rocprof.
// ---------------------------------------------------------------------------
template<int TC_BF16, int MODE>
__global__ __launch_bounds__(256)
void gemm_mfma(const unsigned short* __restrict__ A,
               const unsigned short* __restrict__ Bm,
               void* __restrict__ Cv, int M, int N, int K,
               float scale, const float* __restrict__ bias)
{
    __shared__ char Lraw[32768];
    unsigned short* Al = (unsigned short*)Lraw;            // [2][128*32]
    unsigned short* Bl = (unsigned short*)(Lraw + 16384);  // [2][128*32]
    float* Ot = (float*)Lraw;                              // epilogue [32][132]

    const int tid  = threadIdx.x;
    const int lane = tid & 63;
    const int w    = tid >> 6;
    const int wx   = w & 1, wy = w >> 1;
    int bx, by;
    {
        int nx = gridDim.x;
        int bid = blockIdx.y * nx + blockIdx.x;
        int rpx = gridDim.y >> 3;
        int xcd = bid & 7, idx = bid >> 3;
        by = xcd * rpx + idx / nx;
        bx = idx % nx;
    }
    const int rowBase = by * 128;
    const int colBase = bx * 128;
    const int l15  = lane & 15;
    const int quad = lane >> 4;
    const int srow = lane >> 2;
    const int gch  = (lane & 3) ^ ((srow >> 1) & 3);
    const int swz  = (l15 >> 1) & 3;

    f32x4 acc[4][4] = {};

    #pragma unroll
    for (int it = 0; it < 2; it++) {
        int rb = it*64 + w*16;
        gld16(&Al[rb*32], A  + (size_t)(rowBase + rb + srow)*K + gch*8);
        gld16(&Bl[rb*32], Bm + (size_t)(colBase + rb + srow)*K + gch*8);
    }

    for (int k0 = 0; k0 < K; k0 += 32) {
        const int cur = (k0 >> 5) & 1;
        __syncthreads();
        if (k0 + 32 < K) {
            #pragma unroll
            for (int it = 0; it < 2; it++) {
                int rb = it*64 + w*16;
                gld16(&Al[(1-cur)*4096 + rb*32], A  + (size_t)(rowBase + rb + srow)*K + k0 + 32 + gch*8);
                gld16(&Bl[(1-cur)*4096 + rb*32], Bm + (size_t)(colBase + rb + srow)*K + k0 + 32 + gch*8);
            }
        }
        short8 af[4], bfr[4];
        #pragma unroll
        for (int mi = 0; mi < 4; mi++)
            af[mi] = *(const short8*)&Al[cur*4096 + (wy*64 + mi*16 + l15)*32 + ((quad ^ swz) << 3)];
        #pragma unroll
        for (int ni = 0; ni < 4; ni++)
            bfr[ni] = *(const short8*)&Bl[cur*4096 + (wx*64 + ni*16 + l15)*32 + ((quad ^ swz) << 3)];
        #pragma unroll
        for (int mi = 0; mi < 4; mi++)
            #pragma unroll
            for (int ni = 0; ni < 4; ni++)
                acc[mi][ni] = __builtin_amdgcn_mfma_f32_16x16x32_bf16(
                    af[mi], bfr[ni], acc[mi][ni], 0, 0, 0);
    }

    #pragma unroll
    for (int mi = 0; mi < 4; mi++) {
        __syncthreads();
        #pragma unroll
        for (int ni = 0; ni < 4; ni++) {
            #pragma unroll
            for (int r = 0; r < 4; r++) {
                float v = acc[mi][ni][r] * scale;
                if (MODE == 1) {
                    int row = rowBase + wy*64 + mi*16 + quad*4 + r;
                    int col = colBase + wx*64 + ni*16 + l15;
                    int s = row & (S_ - 1);
                    float freq = __expf(-0.017988946039244957f * (float)(col & ~1));
                    float ang = (float)s * freq;
                    v += bias[col] + ((col & 1) ? cosf(ang) : sinf(ang));
                }
                Ot[(wy*16 + quad*4 + r)*132 + wx*64 + ni*16 + l15] = v;
            }
        }
        __syncthreads();
        {
            int rl = tid >> 3, c0 = (tid & 7) * 16;
            int grow = rowBase + (rl >> 4)*64 + mi*16 + (rl & 15);
            float vv[16];
            #pragma unroll
            for (int j = 0; j < 4; j++)
                *(float4*)&vv[j*4] = *(const float4*)&Ot[rl*132 + c0 + j*4];
            if (TC_BF16) {
                unsigned short u[16] __attribute__((aligned(16)));
                #pragma unroll
                for (int i = 0; i < 16; i++) u[i] = f2bf(vv[i]);
                unsigned short* dst = (unsigned short*)Cv + (size_t)grow*N + colBase + c0;
                *(float4*)dst       = *(float4*)&u[0];
                *(float4*)(dst + 8) = *(float4*)&u[8];
            } else {
                float* dst = (float*)Cv + (size_t)grow*N + colBase + c0;
                #pragma unroll
                for (int j = 0; j < 4; j++)
                    *(float4*)(dst + j*4) = *(const float4*)&vv[j*4];
            }
        }
    }
}

// ---------------------------------------------------------------------------
// Fused Wo-projection + residual + LayerNorm: block = 32 tokens x full 512
// cols, K=64 (WoV), rows complete per block -> LN in-kernel.
// ---------------------------------------------------------------------------
__global__ __launch_bounds__(256)
void wo_ln(const unsigned short* __restrict__ yout,   // [T][64]
           const unsigned short* __restrict__ WoV,    // [E][64]
           unsigned short* __restrict__ h,
           const float* __restrict__ g, const float* __restrict__ b)
{
    __shared__ float Ot[16*520];   // 33 KB; stride 520 (=8 mod 32) vs conflicts
    const int tid  = threadIdx.x;
    const int lane = tid & 63;
    const int w    = tid >> 6;
    const int l15  = lane & 15;
    const int quad = lane >> 4;
    const size_t t0 = (size_t)blockIdx.x * 32;

    // A frags: yout[t][k], m=l15 token-in-tile, k=kb*32+quad*8+j
    short8 af[2][2];
    #pragma unroll
    for (int mi = 0; mi < 2; mi++)
        #pragma unroll
        for (int kb = 0; kb < 2; kb++)
            af[mi][kb] = *(const short8*)&yout[(t0 + mi*16 + l15)*64 + kb*32 + quad*8];

    // B frags: WoV[f][k], n=l15 f-in-tile; wave w covers f in [w*128, w*128+128)
    f32x4 acc[2][8] = {};
    #pragma unroll
    for (int ni = 0; ni < 8; ni++)
        #pragma unroll
        for (int kb = 0; kb < 2; kb++) {
            short8 bf8 = *(const short8*)&WoV[(size_t)(w*128 + ni*16 + l15)*64 + kb*32 + quad*8];
            acc[0][ni] = __builtin_amdgcn_mfma_f32_16x16x32_bf16(af[0][kb], bf8, acc[0][ni], 0, 0, 0);
            acc[1][ni] = __builtin_amdgcn_mfma_f32_16x16x32_bf16(af[1][kb], bf8, acc[1][ni], 0, 0, 0);
        }

    // two rounds of 16 tokens: stage attn rows -> LN -> write h
    #pragma unroll
    for (int p = 0; p < 2; p++) {
        __syncthreads();
        #pragma unroll
        for (int ni = 0; ni < 8; ni++)
            #pragma unroll
            for (int r = 0; r < 4; r++)
                Ot[(quad*4 + r)*520 + w*128 + ni*16 + l15] = acc[p][ni][r];
        __syncthreads();
        const int tk = tid >> 4, u = tid & 15;      // 16 threads per token
        const size_t trow = t0 + p*16 + tk;
        float x[32];
        float s = 0.f, sq = 0.f;
        #pragma unroll
        for (int j = 0; j < 8; j++) {
            int c = u*4 + j*64;                     // interleaved: 2-way banks
            ushort4 hv = *(const ushort4*)&h[trow*E_ + c];
            float4 at = *(const float4*)&Ot[tk*520 + c];
            float v0 = bf2f(hv.x) + at.x;
            float v1 = bf2f(hv.y) + at.y;
            float v2 = bf2f(hv.z) + at.z;
            float v3 = bf2f(hv.w) + at.w;
            x[j*4+0] = v0; x[j*4+1] = v1; x[j*4+2] = v2; x[j*4+3] = v3;
            s  += v0 + v1 + v2 + v3;
            sq += v0*v0 + v1*v1 + v2*v2 + v3*v3;
        }
        #pragma unroll
        for (int off = 1; off < 16; off <<= 1) {
            s  += __shfl_xor(s,  off);
            sq += __shfl_xor(sq, off);
        }
        float mu   = s * (1.f/E_);
        float var  = sq * (1.f/E_) - mu*mu;
        float rstd = rsqrtf(var + 1e-5f);
        #pragma unroll
        for (int j = 0; j < 8; j++) {
            int c = u*4 + j*64;
            float4 gv = *(const float4*)&g[c];
            float4 bv = *(const float4*)&b[c];
            ushort4 ov;
            ov.x = f2bf((x[j*4+0] - mu)*rstd*gv.x + bv.x);
            ov.y = f2bf((x[j*4+1] - mu)*rstd*gv.y + bv.y);
            ov.z = f2bf((x[j*4+2] - mu)*rstd*gv.z + bv.z);
            ov.w = f2bf((x[j*4+3] - mu)*rstd*gv.w + bv.w);
            *(ushort4*)&h[trow*E_ + c] = ov;
        }
    }
}

// ---------------------------------------------------------------------------
// Fused ffn1 + W2 GEMM (h bf16): tmp^T = W2 . relu(W1 . cos8^T).
// v5: NO LDS staging for W2 -- B-fragments are read directly from global
// (W2b is 2 MB, L2-resident per XCD). No barriers in the K loop; LDS only
// for the epilogue. Geometry = proven v4 (1024 blocks, 128e x 64tok).
// ---------------------------------------------------------------------------
__global__ __launch_bounds__(256)
void gemm_w2f(const unsigned short* __restrict__ h, const float* __restrict__ phi,
              const unsigned short* __restrict__ W1b,   // [FFN][8] bf16
              const unsigned short* __restrict__ W2b,   // [E][FFN] bf16
              unsigned short* __restrict__ tmp)          // [T][E] bf16
{
    __shared__ float Ot[64*33];   // 8448 B epilogue only

    const int tid  = threadIdx.x;
    const int lane = tid & 63;
    const int w    = tid >> 6;
    const int tx   = w & 1, ty = w >> 1;
    const int l15  = lane & 15;
    const int quad = lane >> 4;

    const int bid = blockIdx.x;
    const int xcd = bid & 7;
    const int eb  = xcd >> 1;
    const int tb  = (xcd & 1) * 128 + (bid >> 3);
    const int tBase = tb * 64;
    const int eBase = eb * 128;

    short4v cosfr[2];
    #pragma unroll
    for (int nt = 0; nt < 2; nt++) {
        short4v c = {0,0,0,0};
        if (quad < 2) {
            int tok = tBase + ty*32 + nt*16 + l15;
            #pragma unroll
            for (int i = 0; i < 4; i++) {
                int wv = quad*4 + i;
                c[i] = (short)f2bf(cosf(bf2f(h[(size_t)tok*E_ + wv]) + phi[wv]));
            }
        }
        cosfr[nt] = c;
    }

    const f32x4 fzero = {0.f, 0.f, 0.f, 0.f};
    f32x4 acc[4][2] = {};   // acc[et][nt]: col=token(l15), row=e(quad*4+r)

    // per-lane W2 base: row = eBase + tx*64 + et*16 + l15, col chunk = quad*8
    const unsigned short* wbase = W2b + (size_t)(eBase + tx*64 + l15)*FFN_ + quad*8;

    #pragma unroll 2
    for (int k0 = 0; k0 < FFN_; k0 += 32) {
        // ffn1 -> relu -> bf16 pack -> quad-transpose (verified path)
        short4v w1f[2] = {{0,0,0,0},{0,0,0,0}};
        #pragma unroll
        for (int jb = 0; jb < 2; jb++)
            if (quad < 2)
                w1f[jb] = *(const short4v*)&W1b[(size_t)(k0 + jb*16 + l15)*NW_ + quad*4];
        short8 pfr[2];
        #pragma unroll
        for (int nt = 0; nt < 2; nt++) {
            unsigned Pm[4];
            #pragma unroll
            for (int jb = 0; jb < 2; jb++) {
                f32x4 c = mfma16(w1f[jb], cosfr[nt], fzero);
                Pm[jb*2]   = cvtpk_bf16(fmaxf(c[0], 0.f), fmaxf(c[1], 0.f));
                Pm[jb*2+1] = cvtpk_bf16(fmaxf(c[2], 0.f), fmaxf(c[3], 0.f));
            }
            lswap32(Pm[0], Pm[2]); lswap32(Pm[1], Pm[3]);
            lswap16(Pm[0], Pm[2]); lswap16(Pm[1], Pm[3]);
            uint4v u = { Pm[0], Pm[1], Pm[2], Pm[3] };
            pfr[nt] = __builtin_bit_cast(short8, u);
        }
        // main: full K=32, W2 B-fragments straight from L2
        #pragma unroll
        for (int et = 0; et < 4; et++) {
            short8 wf = *(const short8*)(wbase + (size_t)et*16*FFN_ + k0);
            #pragma unroll
            for (int nt = 0; nt < 2; nt++)
                acc[et][nt] = __builtin_amdgcn_mfma_f32_16x16x32_bf16(
                    wf, pfr[nt], acc[et][nt], 0, 0, 0);
        }
    }

    #pragma unroll
    for (int et = 0; et < 4; et++) {
        __syncthreads();
        #pragma unroll
        for (int nt = 0; nt < 2; nt++)
            #pragma unroll
            for (int r = 0; r < 4; r++)
                Ot[(ty*32 + nt*16 + l15)*33 + tx*16 + quad*4 + r] = acc[et][nt][r];
        __syncthreads();
        int token = tid >> 2, q4 = tid & 3;
        unsigned short u[8] __attribute__((aligned(16)));
        #pragma unroll
        for (int i = 0; i < 8; i++) u[i] = f2bf(Ot[token*33 + q4*8 + i]);
        unsigned short* dst = tmp + (size_t)(tBase + token)*E_ + eBase
                              + (q4 >> 1)*64 + et*16 + (q4 & 1)*8;
        *(float4*)dst = *(float4*)&u[0];
    }
}

// ---------------------------------------------------------------------------
// Rank-8 flash attention: S = c8_q^T G c8_k via K=16 MFMA on gk=G.c8;
// PV accumulates y = P.c8 in 8-dim quantum space (+ones row -> rowsum).
// No LDS, no barriers; gk/c8 tiles are L2-resident (bb==xcd under swizzle).
// ---------------------------------------------------------------------------
__global__ __launch_bounds__(256)
void flash_q(const unsigned short* __restrict__ c8,
             const unsigned short* __restrict__ c8T,
             const unsigned short* __restrict__ gkb,
             unsigned short* __restrict__ yout)
{
    const int tid  = threadIdx.x;
    const int lane = tid & 63;
    const int wv   = tid >> 6;
    const int l15  = lane & 15;
    const int quad = lane >> 4;
    const int bid  = blockIdx.x;
    const int xcd  = bid & 7;
    const int rest = bid >> 3;
    const int combo = xcd * 8 + (rest >> 4);
    const int qt = rest & 15;
    const int hh = combo & 7;
    const int bb = combo >> 3;
    const size_t qrow0 = (size_t)bb*S_ + (size_t)qt*128;
    const unsigned short* gkp  = gkb + (size_t)(bb*H_ + hh)*S_*NW_;
    const unsigned short* c8Tp = c8T + (size_t)bb*8*S_;

    short4v cqfr[2] = {{0,0,0,0},{0,0,0,0}};
    if (quad < 2) {
        #pragma unroll
        for (int mi = 0; mi < 2; mi++)
            cqfr[mi] = *(const short4v*)&c8[(qrow0 + wv*32 + mi*16 + l15)*NW_ + quad*4];
    }
    const short8 ones8 = {(short)0x3F80, (short)0x3F80, (short)0x3F80, (short)0x3F80,
                          (short)0x3F80, (short)0x3F80, (short)0x3F80, (short)0x3F80};
    f32x4 y[2] = {};

    for (int kt = 0; kt < S_/64; kt++) {
        f32x4 Sc[2][4] = {};
        #pragma unroll
        for (int nt = 0; nt < 4; nt++) {
            short4v gkf = {0,0,0,0};
            if (quad < 2)
                gkf = *(const short4v*)&gkp[(size_t)(kt*64 + nt*16 + l15)*NW_ + quad*4];
            Sc[0][nt] = mfma16(gkf, cqfr[0], Sc[0][nt]);
            Sc[1][nt] = mfma16(gkf, cqfr[1], Sc[1][nt]);
        }
        unsigned Pm[2][8];
        #pragma unroll
        for (int mi = 0; mi < 2; mi++)
            #pragma unroll
            for (int nt = 0; nt < 4; nt++) {
                float e0 = __builtin_amdgcn_exp2f(Sc[mi][nt][0]);
                float e1 = __builtin_amdgcn_exp2f(Sc[mi][nt][1]);
                float e2 = __builtin_amdgcn_exp2f(Sc[mi][nt][2]);
                float e3 = __builtin_amdgcn_exp2f(Sc[mi][nt][3]);
                Pm[mi][nt*2]   = cvtpk_bf16(e0, e1);
                Pm[mi][nt*2+1] = cvtpk_bf16(e2, e3);
            }
        #pragma unroll
        for (int mi = 0; mi < 2; mi++) {
            lswap32(Pm[mi][0], Pm[mi][2]); lswap32(Pm[mi][1], Pm[mi][3]);
            lswap32(Pm[mi][4], Pm[mi][6]); lswap32(Pm[mi][5], Pm[mi][7]);
            lswap16(Pm[mi][0], Pm[mi][2]); lswap16(Pm[mi][1], Pm[mi][3]);
            lswap16(Pm[mi][4], Pm[mi][6]); lswap16(Pm[mi][5], Pm[mi][7]);
        }
        short8 pf[2][2];
        #pragma unroll
        for (int mi = 0; mi < 2; mi++)
            #pragma unroll
            for (int kb = 0; kb < 2; kb++) {
                uint4v u = { Pm[mi][kb*4], Pm[mi][kb*4+1], Pm[mi][kb*4+2], Pm[mi][kb*4+3] };
                pf[mi][kb] = __builtin_bit_cast(short8, u);
            }
        #pragma unroll
        for (int kb = 0; kb < 2; kb++) {
            short8 a8 = {0,0,0,0,0,0,0,0};
            if (l15 < 8)
                a8 = *(const short8*)&c8Tp[(size_t)l15*S_ + kt*64 + kb*32 + quad*8];
            else if (l15 == 8)
                a8 = ones8;
            y[0] = __builtin_amdgcn_mfma_f32_16x16x32_bf16(a8, pf[0][kb], y[0], 0, 0, 0);
            y[1] = __builtin_amdgcn_mfma_f32_16x16x32_bf16(a8, pf[1][kb], y[1], 0, 0, 0);
        }
    }

    #pragma unroll
    for (int mi = 0; mi < 2; mi++) {
        float rs = __shfl(y[mi][0], 32 + l15);
        float inv = 1.f / rs;
        if (quad < 2) {
            unsigned d0 = cvtpk_bf16(y[mi][0]*inv, y[mi][1]*inv);
            unsigned d1 = cvtpk_bf16(y[mi][2]*inv, y[mi][3]*inv);
            unsigned* dst = (unsigned*)&yout[(qrow0 + wv*32 + mi*16 + l15)*64 + hh*8 + quad*4];
            dst[0] = d0; dst[1] = d1;
        }
    }
}

// ---------------------------------------------------------------------------
// h = LayerNorm(h + delta) * g + b  (h bf16; one wave per token, no barriers)
// ---------------------------------------------------------------------------
__global__ __launch_bounds__(256)
void add_ln(unsigned short* __restrict__ h, const unsigned short* __restrict__ delta,
            const float* __restrict__ g, const float* __restrict__ b)
{
    const int lane = threadIdx.x & 63;
    const int t = blockIdx.x*4 + (threadIdx.x >> 6);
    const size_t base = (size_t)t*E_ + lane*8;
    uint4 hv = *(const uint4*)&h[base];
    uint4 dv = *(const uint4*)&delta[base];
    float x[8];
    #pragma unroll
    for (int i = 0; i < 4; i++) {
        unsigned hu = ((const unsigned*)&hv)[i], du = ((const unsigned*)&dv)[i];
        x[2*i]   = bf2f((unsigned short)(hu & 0xffff)) + bf2f((unsigned short)(du & 0xffff));
        x[2*i+1] = bf2f((unsigned short)(hu >> 16))    + bf2f((unsigned short)(du >> 16));
    }
    float s = 0.f, sq = 0.f;
    #pragma unroll
    for (int i = 0; i < 8; i++) { s += x[i]; sq += x[i]*x[i]; }
    #pragma unroll
    for (int off = 1; off < 64; off <<= 1) {
        s  += __shfl_xor(s,  off);
        sq += __shfl_xor(sq, off);
    }
    float mu  = s * (1.f/E_);
    float var = sq * (1.f/E_) - mu*mu;
    float rstd = rsqrtf(var + 1e-5f);
    float4 g0 = *(const float4*)&g[lane*8], g1 = *(const float4*)&g[lane*8 + 4];
    float4 b0 = *(const float4*)&b[lane*8], b1 = *(const float4*)&b[lane*8 + 4];
    float gg[8] = {g0.x,g0.y,g0.z,g0.w,g1.x,g1.y,g1.z,g1.w};
    float bb[8] = {b0.x,b0.y,b0.z,b0.w,b1.x,b1.y,b1.z,b1.w};
    uint4 ov;
    #pragma unroll
    for (int i = 0; i < 4; i++) {
        unsigned lo = f2bf((x[2*i]   - mu)*rstd*gg[2*i]   + bb[2*i]);
        unsigned hi = f2bf((x[2*i+1] - mu)*rstd*gg[2*i+1] + bb[2*i+1]);
        ((unsigned*)&ov)[i] = lo | (hi << 16);
    }
    *(uint4*)&h[base] = ov;
}

__global__ __launch_bounds__(256)
void pool_partial(const unsigned short* __restrict__ h, float* __restrict__ part)
{
    const int chunk = blockIdx.x, bb = blockIdx.y, tid = threadIdx.x;
    for (int e = tid; e < E_; e += 256) {
        const unsigned short* p = h + ((size_t)bb*S_ + (size_t)chunk*128)*E_ + e;
        float s = 0.f;
        for (int r = 0; r < 128; r++) s += bf2f(p[(size_t)r*E_]);
        part[(size_t)(bb*16 + chunk)*E_ + e] = s;
    }
}

__global__ __launch_bounds__(256)
void pool_final(const float* __restrict__ part, float* __restrict__ pooled)
{
    const int bb = blockIdx.x, tid = threadIdx.x;
    for (int e = tid; e < E_; e += 256) {
        float s = 0.f;
        #pragma unroll
        for (int c = 0; c < 16; c++) s += part[(size_t)(bb*16 + c)*E_ + e];
        pooled[bb*E_ + e] = s * (1.f/S_);
    }
}

__global__ __launch_bounds__(64)
void classify(const float* __restrict__ pooled, const float* __restrict__ Wc,
              const float* __restrict__ bc, float* __restrict__ out)
{
    const int c = blockIdx.x, bb = blockIdx.y, lane = threadIdx.x;
    const float* p = pooled + bb*E_;
    const float* wc = Wc + (size_t)c*E_;
    float s = 0.f;
    for (int e = lane; e < E_; e += 64) s += p[e]*wc[e];
    #pragma unroll
    for (int off = 1; off < 64; off <<= 1) s += __shfl_xor(s, off);
    if (lane == 0) out[bb*NC_ + c] = s + bc[c];
}

// ---------------------------------------------------------------------------
extern "C" void kernel_launch(void* const* d_in, const int* in_sizes, int n_in,
                              void* d_out, int out_size, void* d_ws, size_t ws_size,
                              hipStream_t stream)
{
    const float* x       = (const float*)d_in[0];
    const float* Wi      = (const float*)d_in[1];
    const float* bi      = (const float*)d_in[2];
    const float* theta_a = (const float*)d_in[3];
    const float* Wproj   = (const float*)d_in[4];
    const float* Wq      = (const float*)d_in[5];
    const float* Wk      = (const float*)d_in[6];
    const float* Wv      = (const float*)d_in[7];
    const float* Wo      = (const float*)d_in[8];
    const float* g1      = (const float*)d_in[9];
    const float* b1      = (const float*)d_in[10];
    const float* phi     = (const float*)d_in[11];
    const float* W1      = (const float*)d_in[12];
    const float* W2      = (const float*)d_in[13];
    const float* g2      = (const float*)d_in[14];
    const float* b2      = (const float*)d_in[15];
    const float* Wc      = (const float*)d_in[16];
    const float* bc      = (const float*)d_in[17];
    float* out = (float*)d_out;

    char* ws = (char*)d_ws;
    const size_t MB = 1024u*1024u;
    unsigned short* h      = (unsigned short*)(ws + 0*MB);    // 16 MB bf16
    unsigned short* tmp    = (unsigned short*)(ws + 16*MB);   // 16 MB bf16
    unsigned short* c8     = (unsigned short*)(ws + 32*MB);   // 256 KB [T][8]
    unsigned short* c8T    = (unsigned short*)(ws + 33*MB);   // 256 KB [B][8][S]
    unsigned short* gkb    = (unsigned short*)(ws + 34*MB);   // 2 MB  [B][H][S][8]
    unsigned short* yout   = (unsigned short*)(ws + 48*MB);   // 2 MB  [T][64]
    unsigned short* xb     = (unsigned short*)(ws + 96*MB);   // 8 MB
    unsigned short* Wib    = (unsigned short*)(ws + 104*MB);  // 256 KB
    unsigned short* W2b    = (unsigned short*)(ws + 106*MB);  // 4 MB (both layers)
    unsigned short* W1b    = (unsigned short*)(ws + 110*MB);  // 64 KB (both layers)
    unsigned short* Weff   = (unsigned short*)(ws + 111*MB);  // 48 KB
    unsigned short* Gbuf   = (unsigned short*)(ws + 111*MB + 64*1024);   // 2 KB [2][8][8][8]
    unsigned short* WoV    = (unsigned short*)(ws + 111*MB + 128*1024);  // 128 KB [2][E][64]
    float*          part   = (float*)(ws + 112*MB);           // 256 KB
    float*          pooled = (float*)(ws + 112*MB + 512*1024);

    // 0. bulk fp32->bf16 conversion + effective weights + Gram/WoV folds
    cvt_all<<<6304, 256, 0, stream>>>(x, Wi, W2, W1, xb, Wib, W2b, W1b);
    weff_kernel<<<dim3(E_, 2, 3), 64, 0, stream>>>(Wq, Wk, Wv, Wproj, Weff);
    gram_kernel<<<dim3(H_, 2), 64, 0, stream>>>(Weff, Gbuf);
    wov_kernel<<<dim3(E_, 2), 64, 0, stream>>>(Wo, Weff, WoV);

    // 1. h = x @ Wi^T + bi + posenc  (bf16 h)
    gemm_mfma<1,1><<<dim3(E_/128, T_/128), 256, 0, stream>>>(
        xb, Wib, h, T_, E_, FIN, 1.f, bi);

    for (int l = 0; l < 2; l++) {
        // quantum attention sublayer (rank-8 path, fused Wo+LN)
        qc_small<<<T_/32, 256, 0, stream>>>(h, theta_a + l*NW_, Gbuf + (size_t)l*512,
                                            c8, c8T, gkb);
        flash_q<<<(S_/128)*H_*B_, 256, 0, stream>>>(c8, c8T, gkb, yout);
        wo_ln<<<T_/32, 256, 0, stream>>>(yout, WoV + (size_t)l*E_*64, h,
                                         g1 + l*E_, b1 + l*E_);

        // quantum feed-forward sublayer (ffn1 + W2, W2 direct from L2)
        gemm_w2f<<<1024, 256, 0, stream>>>(h, phi + l*NW_,
                                           W1b + (size_t)l*FFN_*NW_,
                                           W2b + (size_t)l*E_*FFN_, tmp);
        add_ln<<<T_/4, 256, 0, stream>>>(h, tmp, g2 + l*E_, b2 + l*E_);
    }

    // pooled mean over seq, then classifier
    pool_partial<<<dim3(16, B_), 256, 0, stream>>>(h, part);
    pool_final<<<B_, 256, 0, stream>>>(part, pooled);
    classify<<<dim3(NC_, B_), 64, 0, stream>>>(pooled, Wc, bc, out);
}

// Round 10
// 558.925 us; speedup vs baseline: 1.2551x; 1.2551x over previous
//
#include <hip/hip_runtime.h>
#include <hip/hip_bf16.h>
#include <math.h>

#define B_   8
#define S_   2048
#define T_   (B_*S_)      // 16384 tokens
#define FIN  256
#define E_   512
#define H_   8
#define D_   64
#define FFN_ 2048
#define NC_  1000
#define NW_  8

typedef __attribute__((ext_vector_type(8))) short short8;
typedef __attribute__((ext_vector_type(4))) short short4v;
typedef __attribute__((ext_vector_type(4))) float f32x4;
typedef __attribute__((ext_vector_type(2))) unsigned int uint2v;
typedef __attribute__((ext_vector_type(4))) unsigned int uint4v;

__device__ __forceinline__ unsigned short f2bf(float f) {
    __hip_bfloat16 h = __float2bfloat16(f);
    return __builtin_bit_cast(unsigned short, h);
}
__device__ __forceinline__ float bf2f(unsigned short u) {
    return __builtin_bit_cast(float, (unsigned int)u << 16);
}

// packed f32x2 -> bf16x2 (single VALU instr; no builtin on gfx950)
__device__ __forceinline__ unsigned cvtpk_bf16(float lo, float hi) {
    unsigned r;
    asm("v_cvt_pk_bf16_f32 %0, %1, %2" : "=v"(r) : "v"(lo), "v"(hi));
    return r;
}

#if defined(__has_builtin)
#if __has_builtin(__builtin_amdgcn_permlane32_swap) && __has_builtin(__builtin_amdgcn_permlane16_swap)
#define HAVE_PLSWAP 1
#endif
#endif

// exchange lane-bit 5 (xor32) with the a/b register bit
__device__ __forceinline__ void lswap32(unsigned &a, unsigned &b) {
#if defined(HAVE_PLSWAP)
    uint2v t = __builtin_amdgcn_permlane32_swap(a, b, false, false);
    a = t[0]; b = t[1];
#else
    unsigned as = (unsigned)__shfl_xor((int)a, 32);
    unsigned bs = (unsigned)__shfl_xor((int)b, 32);
    bool hi = (threadIdx.x & 32) != 0;
    unsigned na = hi ? bs : a;
    unsigned nb = hi ? b  : as;
    a = na; b = nb;
#endif
}
// exchange lane-bit 4 (xor16) with the a/b register bit
__device__ __forceinline__ void lswap16(unsigned &a, unsigned &b) {
#if defined(HAVE_PLSWAP)
    uint2v t = __builtin_amdgcn_permlane16_swap(a, b, false, false);
    a = t[0]; b = t[1];
#else
    unsigned as = (unsigned)__shfl_xor((int)a, 16);
    unsigned bs = (unsigned)__shfl_xor((int)b, 16);
    bool hi = (threadIdx.x & 16) != 0;
    unsigned na = hi ? bs : a;
    unsigned nb = hi ? b  : as;
    a = na; b = nb;
#endif
}

// async global->LDS, 16B per lane; LDS dest = wave-uniform base + lane*16
__device__ __forceinline__ void gld16(void* l, const void* g) {
    __builtin_amdgcn_global_load_lds(
        (const __attribute__((address_space(1))) unsigned int*)g,
        (__attribute__((address_space(3))) unsigned int*)l,
        16, 0, 0);
}

#if defined(__has_builtin)
#if __has_builtin(__builtin_amdgcn_mfma_f32_16x16x16bf16_1k)
#define HAVE_MFMA16 1
#endif
#endif

// K=16 bf16 MFMA: A[m=lane&15][k=quad*4+j]; B[n=lane&15][k=quad*4+j];
// C col=lane&15(n), row=quad*4+r(m)
__device__ __forceinline__ f32x4 mfma16(short4v a, short4v b, f32x4 c) {
#ifdef HAVE_MFMA16
    return __builtin_amdgcn_mfma_f32_16x16x16bf16_1k(a, b, c, 0, 0, 0);
#else
    short8 a8 = {a[0], a[1], a[2], a[3], 0, 0, 0, 0};
    short8 b8 = {b[0], b[1], b[2], b[3], 0, 0, 0, 0};
    return __builtin_amdgcn_mfma_f32_16x16x32_bf16(a8, b8, c, 0, 0, 0);
#endif
}

// ---------------------------------------------------------------------------
// fp32 -> bf16 bulk conversion: x | Wi | W2(2l) | W1(2l).
// float4 prefix: 1048576 | 1081344 | 1605632 | 1613824 -> 6304 blocks
// ---------------------------------------------------------------------------
__global__ __launch_bounds__(256)
void cvt_all(const float* __restrict__ x,  const float* __restrict__ Wi,
             const float* __restrict__ W2, const float* __restrict__ W1,
             unsigned short* xb, unsigned short* Wib,
             unsigned short* W2b, unsigned short* W1b)
{
    int g = blockIdx.x*256 + threadIdx.x;
    const float* s; unsigned short* d; int o;
    if      (g < 1048576) { s = x;  d = xb;  o = g; }
    else if (g < 1081344) { s = Wi; d = Wib; o = g - 1048576; }
    else if (g < 1605632) { s = W2; d = W2b; o = g - 1081344; }
    else                  { s = W1; d = W1b; o = g - 1605632; }
    float4 vv = ((const float4*)s)[o];
    ushort4 u;
    u.x = f2bf(vv.x); u.y = f2bf(vv.y); u.z = f2bf(vv.z); u.w = f2bf(vv.w);
    ((ushort4*)d)[o] = u;
}

// ---------------------------------------------------------------------------
// Weff[which][l][f][w] = scale * sum_e W[l][f][e] * Wproj[l][e][w]  -> bf16
// ---------------------------------------------------------------------------
__global__ __launch_bounds__(64)
void weff_kernel(const float* __restrict__ Wq, const float* __restrict__ Wk,
                 const float* __restrict__ Wv, const float* __restrict__ Wproj,
                 unsigned short* __restrict__ Weff)
{
    const int f = blockIdx.x, l = blockIdx.y, which = blockIdx.z;
    const int lane = threadIdx.x;
    const float* W = (which == 0 ? Wq : which == 1 ? Wk : Wv)
                     + (size_t)l*E_*E_ + (size_t)f*E_;
    const float* P = Wproj + (size_t)l*E_*NW_;
    const int wv = lane & 7;
    float s = 0.f;
    for (int e = (lane >> 3)*64; e < (lane >> 3)*64 + 64; e++)
        s += W[e] * P[e*NW_ + wv];
    #pragma unroll
    for (int off = 8; off < 64; off <<= 1) s += __shfl_xor(s, off);
    const float scale = (which == 0) ? 0.18033688011112042f : 1.f;
    if (lane < 8)
        Weff[((size_t)(which*2 + l)*E_ + f)*NW_ + lane] = f2bf(s * scale);
}

// ---------------------------------------------------------------------------
// Gram matrix per head: G[l][h][w][w'] = sum_d Weff_q[h*64+d][w]*Weff_k[h*64+d][w']
// ---------------------------------------------------------------------------
__global__ __launch_bounds__(64)
void gram_kernel(const unsigned short* __restrict__ Weff, unsigned short* __restrict__ G)
{
    const int hh = blockIdx.x, l = blockIdx.y;
    const int lane = threadIdx.x;
    const int w = lane >> 3, wp = lane & 7;
    const unsigned short* Wq_e = Weff + (size_t)(0*2 + l)*E_*NW_ + (size_t)hh*64*NW_;
    const unsigned short* Wk_e = Weff + (size_t)(1*2 + l)*E_*NW_ + (size_t)hh*64*NW_;
    float s = 0.f;
    for (int d = 0; d < 64; d++)
        s += bf2f(Wq_e[d*NW_ + w]) * bf2f(Wk_e[d*NW_ + wp]);
    G[(size_t)(l*8 + hh)*64 + w*8 + wp] = f2bf(s);
}

// ---------------------------------------------------------------------------
// WoV[l][f][h*8+w] = sum_d Wo[l][f][h*64+d] * Weff_v[h*64+d][w]
// ---------------------------------------------------------------------------
__global__ __launch_bounds__(64)
void wov_kernel(const float* __restrict__ Wo, const unsigned short* __restrict__ Weff,
                unsigned short* __restrict__ WoV)
{
    const int f = blockIdx.x, l = blockIdx.y;
    const int lane = threadIdx.x;
    const int hh = lane >> 3, w = lane & 7;
    const float* wrow = Wo + (size_t)l*E_*E_ + (size_t)f*E_ + hh*64;
    const unsigned short* Wv_e = Weff + (size_t)(2*2 + l)*E_*NW_ + (size_t)hh*64*NW_;
    float s = 0.f;
    for (int d = 0; d < 64; d++)
        s += wrow[d] * bf2f(Wv_e[d*NW_ + w]);
    WoV[(size_t)(l*E_ + f)*64 + lane] = f2bf(s);
}

// ---------------------------------------------------------------------------
// Quantum-space encode: c8[t][8]=cos(h[..8]+theta); c8T[b][8][s] transposed;
// gk[b][h][s][8] = G_h . c8  (the pre-rotated K vectors).
// ---------------------------------------------------------------------------
__global__ __launch_bounds__(256)
void qc_small(const unsigned short* __restrict__ h, const float* __restrict__ theta,
              const unsigned short* __restrict__ G,
              unsigned short* __restrict__ c8, unsigned short* __restrict__ c8T,
              unsigned short* __restrict__ gkb)
{
    const int tid = threadIdx.x;
    const int t0 = blockIdx.x * 32;
    __shared__ float cs[32][8];
    __shared__ float Gs[512];
    {
        int tl = tid >> 3, wv2 = tid & 7;
        cs[tl][wv2] = cosf(bf2f(h[(size_t)(t0 + tl)*E_ + wv2]) + theta[wv2]);
        Gs[tid]       = bf2f(G[tid]);
        Gs[tid + 256] = bf2f(G[tid + 256]);
    }
    __syncthreads();
    const int tl = tid >> 3, hh = tid & 7;
    const int bb = (t0 + tl) >> 11, ss = (t0 + tl) & (S_ - 1);
    float c[8];
    #pragma unroll
    for (int i = 0; i < 8; i++) c[i] = cs[tl][i];
    unsigned short u[8] __attribute__((aligned(16)));
    #pragma unroll
    for (int w = 0; w < 8; w++) {
        float s = 0.f;
        #pragma unroll
        for (int wp = 0; wp < 8; wp++) s += Gs[hh*64 + w*8 + wp] * c[wp];
        u[w] = f2bf(s);
    }
    *(float4*)&gkb[((size_t)(bb*H_ + hh)*S_ + ss)*8] = *(float4*)u;
    if (tid < 32) {
        unsigned short v[8] __attribute__((aligned(16)));
        #pragma unroll
        for (int i = 0; i < 8; i++) v[i] = f2bf(cs[tid][i]);
        *(float4*)&c8[(size_t)(t0 + tid)*8] = *(float4*)v;
    } else if (tid < 40) {
        int w = tid - 32;
        unsigned short v[32] __attribute__((aligned(16)));
        #pragma unroll
        for (int s = 0; s < 32; s++) v[s] = f2bf(cs[s][w]);
        unsigned short* dst = c8T + ((size_t)(t0 >> 11)*8 + w)*S_ + (t0 & (S_ - 1));
        #pragma unroll
        for (int cq = 0; cq < 4; cq++) *(float4*)(dst + cq*8) = *(float4*)&v[cq*8];
    }
}

// ---------------------------------------------------------------------------
// All-bf16 MFMA GEMM: C = scale*(A[M][K] * W[N][K]^T). 128x128 tile, BK=32,
// double-buffered gld16. XCD swizzle. MODE 1: += bias + posenc.
// LDS-staged vectorized epilogue (float4 stores).
// NOTE: first instance per iteration absorbs harness poison traffic in rocprof.
// ---------------------------------------------------------------------------
template<int TC_BF16, int MODE>
__global__ __launch_bounds__(256)
void gemm_mfma(const unsigned short* __restrict__ A,
               const unsigned short* __restrict__ Bm,
               void* __restrict__ Cv, int M, int N, int K,
               float scale, const float* __restrict__ bias)
{
    __shared__ char Lraw[32768];
    unsigned short* Al = (unsigned short*)Lraw;            // [2][128*32]
    unsigned short* Bl = (unsigned short*)(Lraw + 16384);  // [2][128*32]
    float* Ot = (float*)Lraw;                              // epilogue [32][132]

    const int tid  = threadIdx.x;
    const int lane = tid & 63;
    const int w    = tid >> 6;
    const int wx   = w & 1, wy = w >> 1;
    int bx, by;
    {
        int nx = gridDim.x;
        int bid = blockIdx.y * nx + blockIdx.x;
        int rpx = gridDim.y >> 3;
        int xcd = bid & 7, idx = bid >> 3;
        by = xcd * rpx + idx / nx;
        bx = idx % nx;
    }
    const int rowBase = by * 128;
    const int colBase = bx * 128;
    const int l15  = lane & 15;
    const int quad = lane >> 4;
    const int srow = lane >> 2;
    const int gch  = (lane & 3) ^ ((srow >> 1) & 3);
    const int swz  = (l15 >> 1) & 3;

    f32x4 acc[4][4] = {};

    #pragma unroll
    for (int it = 0; it < 2; it++) {
        int rb = it*64 + w*16;
        gld16(&Al[rb*32], A  + (size_t)(rowBase + rb + srow)*K + gch*8);
        gld16(&Bl[rb*32], Bm + (size_t)(colBase + rb + srow)*K + gch*8);
    }

    for (int k0 = 0; k0 < K; k0 += 32) {
        const int cur = (k0 >> 5) & 1;
        __syncthreads();
        if (k0 + 32 < K) {
            #pragma unroll
            for (int it = 0; it < 2; it++) {
                int rb = it*64 + w*16;
                gld16(&Al[(1-cur)*4096 + rb*32], A  + (size_t)(rowBase + rb + srow)*K + k0 + 32 + gch*8);
                gld16(&Bl[(1-cur)*4096 + rb*32], Bm + (size_t)(colBase + rb + srow)*K + k0 + 32 + gch*8);
            }
        }
        short8 af[4], bfr[4];
        #pragma unroll
        for (int mi = 0; mi < 4; mi++)
            af[mi] = *(const short8*)&Al[cur*4096 + (wy*64 + mi*16 + l15)*32 + ((quad ^ swz) << 3)];
        #pragma unroll
        for (int ni = 0; ni < 4; ni++)
            bfr[ni] = *(const short8*)&Bl[cur*4096 + (wx*64 + ni*16 + l15)*32 + ((quad ^ swz) << 3)];
        #pragma unroll
        for (int mi = 0; mi < 4; mi++)
            #pragma unroll
            for (int ni = 0; ni < 4; ni++)
                acc[mi][ni] = __builtin_amdgcn_mfma_f32_16x16x32_bf16(
                    af[mi], bfr[ni], acc[mi][ni], 0, 0, 0);
    }

    #pragma unroll
    for (int mi = 0; mi < 4; mi++) {
        __syncthreads();
        #pragma unroll
        for (int ni = 0; ni < 4; ni++) {
            #pragma unroll
            for (int r = 0; r < 4; r++) {
                float v = acc[mi][ni][r] * scale;
                if (MODE == 1) {
                    int row = rowBase + wy*64 + mi*16 + quad*4 + r;
                    int col = colBase + wx*64 + ni*16 + l15;
                    int s = row & (S_ - 1);
                    float freq = __expf(-0.017988946039244957f * (float)(col & ~1));
                    float ang = (float)s * freq;
                    v += bias[col] + ((col & 1) ? cosf(ang) : sinf(ang));
                }
                Ot[(wy*16 + quad*4 + r)*132 + wx*64 + ni*16 + l15] = v;
            }
        }
        __syncthreads();
        {
            int rl = tid >> 3, c0 = (tid & 7) * 16;
            int grow = rowBase + (rl >> 4)*64 + mi*16 + (rl & 15);
            float vv[16];
            #pragma unroll
            for (int j = 0; j < 4; j++)
                *(float4*)&vv[j*4] = *(const float4*)&Ot[rl*132 + c0 + j*4];
            if (TC_BF16) {
                unsigned short u[16] __attribute__((aligned(16)));
                #pragma unroll
                for (int i = 0; i < 16; i++) u[i] = f2bf(vv[i]);
                unsigned short* dst = (unsigned short*)Cv + (size_t)grow*N + colBase + c0;
                *(float4*)dst       = *(float4*)&u[0];
                *(float4*)(dst + 8) = *(float4*)&u[8];
            } else {
                float* dst = (float*)Cv + (size_t)grow*N + colBase + c0;
                #pragma unroll
                for (int j = 0; j < 4; j++)
                    *(float4*)(dst + j*4) = *(const float4*)&vv[j*4];
            }
        }
    }
}

// ---------------------------------------------------------------------------
// Fused Wo-projection + residual + LayerNorm: block = 32 tokens x full 512
// cols, K=64 (WoV), rows complete per block -> LN in-kernel.
// ---------------------------------------------------------------------------
__global__ __launch_bounds__(256)
void wo_ln(const unsigned short* __restrict__ yout,   // [T][64]
           const unsigned short* __restrict__ WoV,    // [E][64]
           unsigned short* __restrict__ h,
           const float* __restrict__ g, const float* __restrict__ b)
{
    __shared__ float Ot[16*520];   // 33 KB; stride 520 (=8 mod 32) vs conflicts
    const int tid  = threadIdx.x;
    const int lane = tid & 63;
    const int w    = tid >> 6;
    const int l15  = lane & 15;
    const int quad = lane >> 4;
    const size_t t0 = (size_t)blockIdx.x * 32;

    // A frags: yout[t][k], m=l15 token-in-tile, k=kb*32+quad*8+j
    short8 af[2][2];
    #pragma unroll
    for (int mi = 0; mi < 2; mi++)
        #pragma unroll
        for (int kb = 0; kb < 2; kb++)
            af[mi][kb] = *(const short8*)&yout[(t0 + mi*16 + l15)*64 + kb*32 + quad*8];

    // B frags: WoV[f][k], n=l15 f-in-tile; wave w covers f in [w*128, w*128+128)
    f32x4 acc[2][8] = {};
    #pragma unroll
    for (int ni = 0; ni < 8; ni++)
        #pragma unroll
        for (int kb = 0; kb < 2; kb++) {
            short8 bf8 = *(const short8*)&WoV[(size_t)(w*128 + ni*16 + l15)*64 + kb*32 + quad*8];
            acc[0][ni] = __builtin_amdgcn_mfma_f32_16x16x32_bf16(af[0][kb], bf8, acc[0][ni], 0, 0, 0);
            acc[1][ni] = __builtin_amdgcn_mfma_f32_16x16x32_bf16(af[1][kb], bf8, acc[1][ni], 0, 0, 0);
        }

    // two rounds of 16 tokens: stage attn rows -> LN -> write h
    #pragma unroll
    for (int p = 0; p < 2; p++) {
        __syncthreads();
        #pragma unroll
        for (int ni = 0; ni < 8; ni++)
            #pragma unroll
            for (int r = 0; r < 4; r++)
                Ot[(quad*4 + r)*520 + w*128 + ni*16 + l15] = acc[p][ni][r];
        __syncthreads();
        const int tk = tid >> 4, u = tid & 15;      // 16 threads per token
        const size_t trow = t0 + p*16 + tk;
        float x[32];
        float s = 0.f, sq = 0.f;
        #pragma unroll
        for (int j = 0; j < 8; j++) {
            int c = u*4 + j*64;                     // interleaved: 2-way banks
            ushort4 hv = *(const ushort4*)&h[trow*E_ + c];
            float4 at = *(const float4*)&Ot[tk*520 + c];
            float v0 = bf2f(hv.x) + at.x;
            float v1 = bf2f(hv.y) + at.y;
            float v2 = bf2f(hv.z) + at.z;
            float v3 = bf2f(hv.w) + at.w;
            x[j*4+0] = v0; x[j*4+1] = v1; x[j*4+2] = v2; x[j*4+3] = v3;
            s  += v0 + v1 + v2 + v3;
            sq += v0*v0 + v1*v1 + v2*v2 + v3*v3;
        }
        #pragma unroll
        for (int off = 1; off < 16; off <<= 1) {
            s  += __shfl_xor(s,  off);
            sq += __shfl_xor(sq, off);
        }
        float mu   = s * (1.f/E_);
        float var  = sq * (1.f/E_) - mu*mu;
        float rstd = rsqrtf(var + 1e-5f);
        #pragma unroll
        for (int j = 0; j < 8; j++) {
            int c = u*4 + j*64;
            float4 gv = *(const float4*)&g[c];
            float4 bv = *(const float4*)&b[c];
            ushort4 ov;
            ov.x = f2bf((x[j*4+0] - mu)*rstd*gv.x + bv.x);
            ov.y = f2bf((x[j*4+1] - mu)*rstd*gv.y + bv.y);
            ov.z = f2bf((x[j*4+2] - mu)*rstd*gv.z + bv.z);
            ov.w = f2bf((x[j*4+3] - mu)*rstd*gv.w + bv.w);
            *(ushort4*)&h[trow*E_ + c] = ov;
        }
    }
}

// ---------------------------------------------------------------------------
// Fused ffn1 + W2 GEMM (h bf16): tmp^T = W2 . relu(W1 . cos8^T).
// v4 (PROVEN BEST): 128e x 64tok tiles (1024 blocks, 4 blocks/CU), staged
// double-buffered W2 LDS, ffn1 pipelined one k0 ahead.
// ---------------------------------------------------------------------------
__global__ __launch_bounds__(256)
void gemm_w2f(const unsigned short* __restrict__ h, const float* __restrict__ phi,
              const unsigned short* __restrict__ W1b,   // [FFN][8] bf16
              const unsigned short* __restrict__ W2b,   // [E][FFN] bf16
              unsigned short* __restrict__ tmp)          // [T][E] bf16
{
    __shared__ char Lraw[17408];
    unsigned short* Wl = (unsigned short*)Lraw;   // [2][128*32]
    float* Ot = (float*)Lraw;                     // [64][33] epilogue

    const int tid  = threadIdx.x;
    const int lane = tid & 63;
    const int w    = tid >> 6;
    const int tx   = w & 1, ty = w >> 1;
    const int l15  = lane & 15;
    const int quad = lane >> 4;
    const int srow = lane >> 2;
    const int gch  = (lane & 3) ^ ((srow >> 1) & 3);
    const int swz  = (l15 >> 1) & 3;

    const int bid = blockIdx.x;
    const int xcd = bid & 7;
    const int eb  = xcd >> 1;
    const int tb  = (xcd & 1) * 128 + (bid >> 3);
    const int tBase = tb * 64;
    const int eBase = eb * 128;

    short4v cosfr[2];
    #pragma unroll
    for (int nt = 0; nt < 2; nt++) {
        short4v c = {0,0,0,0};
        if (quad < 2) {
            int tok = tBase + ty*32 + nt*16 + l15;
            #pragma unroll
            for (int i = 0; i < 4; i++) {
                int wv = quad*4 + i;
                c[i] = (short)f2bf(cosf(bf2f(h[(size_t)tok*E_ + wv]) + phi[wv]));
            }
        }
        cosfr[nt] = c;
    }

    #pragma unroll
    for (int it = 0; it < 2; it++) {
        int rb = w*32 + it*16;
        gld16(&Wl[rb*32], W2b + (size_t)(eBase + rb + srow)*FFN_ + gch*8);
    }

    const f32x4 fzero = {0.f, 0.f, 0.f, 0.f};
    short4v w1fA[2] = {{0,0,0,0},{0,0,0,0}};

    auto ffn1_pack = [&](short8* pfr_out) {
        unsigned Pm[2][4];
        #pragma unroll
        for (int nt = 0; nt < 2; nt++) {
            #pragma unroll
            for (int jb = 0; jb < 2; jb++) {
                f32x4 c = mfma16(w1fA[jb], cosfr[nt], fzero);
                Pm[nt][jb*2]   = cvtpk_bf16(fmaxf(c[0], 0.f), fmaxf(c[1], 0.f));
                Pm[nt][jb*2+1] = cvtpk_bf16(fmaxf(c[2], 0.f), fmaxf(c[3], 0.f));
            }
            lswap32(Pm[nt][0], Pm[nt][2]); lswap32(Pm[nt][1], Pm[nt][3]);
            lswap16(Pm[nt][0], Pm[nt][2]); lswap16(Pm[nt][1], Pm[nt][3]);
            uint4v u = { Pm[nt][0], Pm[nt][1], Pm[nt][2], Pm[nt][3] };
            pfr_out[nt] = __builtin_bit_cast(short8, u);
        }
    };
    auto load_w1f = [&](int k0) {
        #pragma unroll
        for (int jb = 0; jb < 2; jb++)
            if (quad < 2)
                w1fA[jb] = *(const short4v*)&W1b[(size_t)(k0 + jb*16 + l15)*NW_ + quad*4];
    };

    load_w1f(0);
    short8 pf_cur[2], pf_next[2];
    ffn1_pack(pf_cur);
    load_w1f(32);

    f32x4 acc[4][2] = {};   // acc[et][nt]: col=token(l15), row=e(quad*4+r)

    for (int k0 = 0; k0 < FFN_; k0 += 32) {
        const int cur = (k0 >> 5) & 1;
        __syncthreads();
        if (k0 + 32 < FFN_) {
            #pragma unroll
            for (int it = 0; it < 2; it++) {
                int rb = w*32 + it*16;
                gld16(&Wl[(1-cur)*4096 + rb*32],
                      W2b + (size_t)(eBase + rb + srow)*FFN_ + k0 + 32 + gch*8);
            }
            ffn1_pack(pf_next);
            if (k0 + 64 < FFN_) load_w1f(k0 + 64);
        }
        #pragma unroll
        for (int et = 0; et < 4; et++) {
            short8 wf = *(const short8*)&Wl[cur*4096 + (tx*64 + et*16 + l15)*32
                                             + ((quad ^ swz) << 3)];
            #pragma unroll
            for (int nt = 0; nt < 2; nt++)
                acc[et][nt] = __builtin_amdgcn_mfma_f32_16x16x32_bf16(
                    wf, pf_cur[nt], acc[et][nt], 0, 0, 0);
        }
        #pragma unroll
        for (int nt = 0; nt < 2; nt++) pf_cur[nt] = pf_next[nt];
    }

    #pragma unroll
    for (int et = 0; et < 4; et++) {
        __syncthreads();
        #pragma unroll
        for (int nt = 0; nt < 2; nt++)
            #pragma unroll
            for (int r = 0; r < 4; r++)
                Ot[(ty*32 + nt*16 + l15)*33 + tx*16 + quad*4 + r] = acc[et][nt][r];
        __syncthreads();
        int token = tid >> 2, q4 = tid & 3;
        unsigned short u[8] __attribute__((aligned(16)));
        #pragma unroll
        for (int i = 0; i < 8; i++) u[i] = f2bf(Ot[token*33 + q4*8 + i]);
        unsigned short* dst = tmp + (size_t)(tBase + token)*E_ + eBase
                              + (q4 >> 1)*64 + et*16 + (q4 & 1)*8;
        *(float4*)dst = *(float4*)&u[0];
    }
}

// ---------------------------------------------------------------------------
// Rank-8 flash attention: S = c8_q^T G c8_k via K=16 MFMA on gk=G.c8;
// PV accumulates y = P.c8 in 8-dim quantum space (+ones row -> rowsum).
// No LDS, no barriers; gk/c8 tiles are L2-resident (bb==xcd under swizzle).
// ---------------------------------------------------------------------------
__global__ __launch_bounds__(256)
void flash_q(const unsigned short* __restrict__ c8,
             const unsigned short* __restrict__ c8T,
             const unsigned short* __restrict__ gkb,
             unsigned short* __restrict__ yout)
{
    const int tid  = threadIdx.x;
    const int lane = tid & 63;
    const int wv   = tid >> 6;
    const int l15  = lane & 15;
    const int quad = lane >> 4;
    const int bid  = blockIdx.x;
    const int xcd  = bid & 7;
    const int rest = bid >> 3;
    const int combo = xcd * 8 + (rest >> 4);
    const int qt = rest & 15;
    const int hh = combo & 7;
    const int bb = combo >> 3;
    const size_t qrow0 = (size_t)bb*S_ + (size_t)qt*128;
    const unsigned short* gkp  = gkb + (size_t)(bb*H_ + hh)*S_*NW_;
    const unsigned short* c8Tp = c8T + (size_t)bb*8*S_;

    short4v cqfr[2] = {{0,0,0,0},{0,0,0,0}};
    if (quad < 2) {
        #pragma unroll
        for (int mi = 0; mi < 2; mi++)
            cqfr[mi] = *(const short4v*)&c8[(qrow0 + wv*32 + mi*16 + l15)*NW_ + quad*4];
    }
    const short8 ones8 = {(short)0x3F80, (short)0x3F80, (short)0x3F80, (short)0x3F80,
                          (short)0x3F80, (short)0x3F80, (short)0x3F80, (short)0x3F80};
    f32x4 y[2] = {};

    for (int kt = 0; kt < S_/64; kt++) {
        f32x4 Sc[2][4] = {};
        #pragma unroll
        for (int nt = 0; nt < 4; nt++) {
            short4v gkf = {0,0,0,0};
            if (quad < 2)
                gkf = *(const short4v*)&gkp[(size_t)(kt*64 + nt*16 + l15)*NW_ + quad*4];
            Sc[0][nt] = mfma16(gkf, cqfr[0], Sc[0][nt]);
            Sc[1][nt] = mfma16(gkf, cqfr[1], Sc[1][nt]);
        }
        unsigned Pm[2][8];
        #pragma unroll
        for (int mi = 0; mi < 2; mi++)
            #pragma unroll
            for (int nt = 0; nt < 4; nt++) {
                float e0 = __builtin_amdgcn_exp2f(Sc[mi][nt][0]);
                float e1 = __builtin_amdgcn_exp2f(Sc[mi][nt][1]);
                float e2 = __builtin_amdgcn_exp2f(Sc[mi][nt][2]);
                float e3 = __builtin_amdgcn_exp2f(Sc[mi][nt][3]);
                Pm[mi][nt*2]   = cvtpk_bf16(e0, e1);
                Pm[mi][nt*2+1] = cvtpk_bf16(e2, e3);
            }
        #pragma unroll
        for (int mi = 0; mi < 2; mi++) {
            lswap32(Pm[mi][0], Pm[mi][2]); lswap32(Pm[mi][1], Pm[mi][3]);
            lswap32(Pm[mi][4], Pm[mi][6]); lswap32(Pm[mi][5], Pm[mi][7]);
            lswap16(Pm[mi][0], Pm[mi][2]); lswap16(Pm[mi][1], Pm[mi][3]);
            lswap16(Pm[mi][4], Pm[mi][6]); lswap16(Pm[mi][5], Pm[mi][7]);
        }
        short8 pf[2][2];
        #pragma unroll
        for (int mi = 0; mi < 2; mi++)
            #pragma unroll
            for (int kb = 0; kb < 2; kb++) {
                uint4v u = { Pm[mi][kb*4], Pm[mi][kb*4+1], Pm[mi][kb*4+2], Pm[mi][kb*4+3] };
                pf[mi][kb] = __builtin_bit_cast(short8, u);
            }
        #pragma unroll
        for (int kb = 0; kb < 2; kb++) {
            short8 a8 = {0,0,0,0,0,0,0,0};
            if (l15 < 8)
                a8 = *(const short8*)&c8Tp[(size_t)l15*S_ + kt*64 + kb*32 + quad*8];
            else if (l15 == 8)
                a8 = ones8;
            y[0] = __builtin_amdgcn_mfma_f32_16x16x32_bf16(a8, pf[0][kb], y[0], 0, 0, 0);
            y[1] = __builtin_amdgcn_mfma_f32_16x16x32_bf16(a8, pf[1][kb], y[1], 0, 0, 0);
        }
    }

    #pragma unroll
    for (int mi = 0; mi < 2; mi++) {
        float rs = __shfl(y[mi][0], 32 + l15);
        float inv = 1.f / rs;
        if (quad < 2) {
            unsigned d0 = cvtpk_bf16(y[mi][0]*inv, y[mi][1]*inv);
            unsigned d1 = cvtpk_bf16(y[mi][2]*inv, y[mi][3]*inv);
            unsigned* dst = (unsigned*)&yout[(qrow0 + wv*32 + mi*16 + l15)*64 + hh*8 + quad*4];
            dst[0] = d0; dst[1] = d1;
        }
    }
}

// ---------------------------------------------------------------------------
// h = LayerNorm(h + delta) * g + b  (h bf16; one wave per token, no barriers)
// ---------------------------------------------------------------------------
__global__ __launch_bounds__(256)
void add_ln(unsigned short* __restrict__ h, const unsigned short* __restrict__ delta,
            const float* __restrict__ g, const float* __restrict__ b)
{
    const int lane = threadIdx.x & 63;
    const int t = blockIdx.x*4 + (threadIdx.x >> 6);
    const size_t base = (size_t)t*E_ + lane*8;
    uint4 hv = *(const uint4*)&h[base];
    uint4 dv = *(const uint4*)&delta[base];
    float x[8];
    #pragma unroll
    for (int i = 0; i < 4; i++) {
        unsigned hu = ((const unsigned*)&hv)[i], du = ((const unsigned*)&dv)[i];
        x[2*i]   = bf2f((unsigned short)(hu & 0xffff)) + bf2f((unsigned short)(du & 0xffff));
        x[2*i+1] = bf2f((unsigned short)(hu >> 16))    + bf2f((unsigned short)(du >> 16));
    }
    float s = 0.f, sq = 0.f;
    #pragma unroll
    for (int i = 0; i < 8; i++) { s += x[i]; sq += x[i]*x[i]; }
    #pragma unroll
    for (int off = 1; off < 64; off <<= 1) {
        s  += __shfl_xor(s,  off);
        sq += __shfl_xor(sq, off);
    }
    float mu  = s * (1.f/E_);
    float var = sq * (1.f/E_) - mu*mu;
    float rstd = rsqrtf(var + 1e-5f);
    float4 g0 = *(const float4*)&g[lane*8], g1 = *(const float4*)&g[lane*8 + 4];
    float4 b0 = *(const float4*)&b[lane*8], b1 = *(const float4*)&b[lane*8 + 4];
    float gg[8] = {g0.x,g0.y,g0.z,g0.w,g1.x,g1.y,g1.z,g1.w};
    float bb[8] = {b0.x,b0.y,b0.z,b0.w,b1.x,b1.y,b1.z,b1.w};
    uint4 ov;
    #pragma unroll
    for (int i = 0; i < 4; i++) {
        unsigned lo = f2bf((x[2*i]   - mu)*rstd*gg[2*i]   + bb[2*i]);
        unsigned hi = f2bf((x[2*i+1] - mu)*rstd*gg[2*i+1] + bb[2*i+1]);
        ((unsigned*)&ov)[i] = lo | (hi << 16);
    }
    *(uint4*)&h[base] = ov;
}

__global__ __launch_bounds__(256)
void pool_partial(const unsigned short* __restrict__ h, float* __restrict__ part)
{
    const int chunk = blockIdx.x, bb = blockIdx.y, tid = threadIdx.x;
    for (int e = tid; e < E_; e += 256) {
        const unsigned short* p = h + ((size_t)bb*S_ + (size_t)chunk*128)*E_ + e;
        float s = 0.f;
        for (int r = 0; r < 128; r++) s += bf2f(p[(size_t)r*E_]);
        part[(size_t)(bb*16 + chunk)*E_ + e] = s;
    }
}

__global__ __launch_bounds__(256)
void pool_final(const float* __restrict__ part, float* __restrict__ pooled)
{
    const int bb = blockIdx.x, tid = threadIdx.x;
    for (int e = tid; e < E_; e += 256) {
        float s = 0.f;
        #pragma unroll
        for (int c = 0; c < 16; c++) s += part[(size_t)(bb*16 + c)*E_ + e];
        pooled[bb*E_ + e] = s * (1.f/S_);
    }
}

__global__ __launch_bounds__(64)
void classify(const float* __restrict__ pooled, const float* __restrict__ Wc,
              const float* __restrict__ bc, float* __restrict__ out)
{
    const int c = blockIdx.x, bb = blockIdx.y, lane = threadIdx.x;
    const float* p = pooled + bb*E_;
    const float* wc = Wc + (size_t)c*E_;
    float s = 0.f;
    for (int e = lane; e < E_; e += 64) s += p[e]*wc[e];
    #pragma unroll
    for (int off = 1; off < 64; off <<= 1) s += __shfl_xor(s, off);
    if (lane == 0) out[bb*NC_ + c] = s + bc[c];
}

// ---------------------------------------------------------------------------
extern "C" void kernel_launch(void* const* d_in, const int* in_sizes, int n_in,
                              void* d_out, int out_size, void* d_ws, size_t ws_size,
                              hipStream_t stream)
{
    const float* x       = (const float*)d_in[0];
    const float* Wi      = (const float*)d_in[1];
    const float* bi      = (const float*)d_in[2];
    const float* theta_a = (const float*)d_in[3];
    const float* Wproj   = (const float*)d_in[4];
    const float* Wq      = (const float*)d_in[5];
    const float* Wk      = (const float*)d_in[6];
    const float* Wv      = (const float*)d_in[7];
    const float* Wo      = (const float*)d_in[8];
    const float* g1      = (const float*)d_in[9];
    const float* b1      = (const float*)d_in[10];
    const float* phi     = (const float*)d_in[11];
    const float* W1      = (const float*)d_in[12];
    const float* W2      = (const float*)d_in[13];
    const float* g2      = (const float*)d_in[14];
    const float* b2      = (const float*)d_in[15];
    const float* Wc      = (const float*)d_in[16];
    const float* bc      = (const float*)d_in[17];
    float* out = (float*)d_out;

    char* ws = (char*)d_ws;
    const size_t MB = 1024u*1024u;
    unsigned short* h      = (unsigned short*)(ws + 0*MB);    // 16 MB bf16
    unsigned short* tmp    = (unsigned short*)(ws + 16*MB);   // 16 MB bf16
    unsigned short* c8     = (unsigned short*)(ws + 32*MB);   // 256 KB [T][8]
    unsigned short* c8T    = (unsigned short*)(ws + 33*MB);   // 256 KB [B][8][S]
    unsigned short* gkb    = (unsigned short*)(ws + 34*MB);   // 2 MB  [B][H][S][8]
    unsigned short* yout   = (unsigned short*)(ws + 48*MB);   // 2 MB  [T][64]
    unsigned short* xb     = (unsigned short*)(ws + 96*MB);   // 8 MB
    unsigned short* Wib    = (unsigned short*)(ws + 104*MB);  // 256 KB
    unsigned short* W2b    = (unsigned short*)(ws + 106*MB);  // 4 MB (both layers)
    unsigned short* W1b    = (unsigned short*)(ws + 110*MB);  // 64 KB (both layers)
    unsigned short* Weff   = (unsigned short*)(ws + 111*MB);  // 48 KB
    unsigned short* Gbuf   = (unsigned short*)(ws + 111*MB + 64*1024);   // 2 KB [2][8][8][8]
    unsigned short* WoV    = (unsigned short*)(ws + 111*MB + 128*1024);  // 128 KB [2][E][64]
    float*          part   = (float*)(ws + 112*MB);           // 256 KB
    float*          pooled = (float*)(ws + 112*MB + 512*1024);

    // 0. bulk fp32->bf16 conversion + effective weights + Gram/WoV folds
    cvt_all<<<6304, 256, 0, stream>>>(x, Wi, W2, W1, xb, Wib, W2b, W1b);
    weff_kernel<<<dim3(E_, 2, 3), 64, 0, stream>>>(Wq, Wk, Wv, Wproj, Weff);
    gram_kernel<<<dim3(H_, 2), 64, 0, stream>>>(Weff, Gbuf);
    wov_kernel<<<dim3(E_, 2), 64, 0, stream>>>(Wo, Weff, WoV);

    // 1. h = x @ Wi^T + bi + posenc  (bf16 h)
    gemm_mfma<1,1><<<dim3(E_/128, T_/128), 256, 0, stream>>>(
        xb, Wib, h, T_, E_, FIN, 1.f, bi);

    for (int l = 0; l < 2; l++) {
        // quantum attention sublayer (rank-8 path, fused Wo+LN)
        qc_small<<<T_/32, 256, 0, stream>>>(h, theta_a + l*NW_, Gbuf + (size_t)l*512,
                                            c8, c8T, gkb);
        flash_q<<<(S_/128)*H_*B_, 256, 0, stream>>>(c8, c8T, gkb, yout);
        wo_ln<<<T_/32, 256, 0, stream>>>(yout, WoV + (size_t)l*E_*64, h,
                                         g1 + l*E_, b1 + l*E_);

        // quantum feed-forward sublayer (fused ffn1 + W2, 64-token tiles)
        gemm_w2f<<<1024, 256, 0, stream>>>(h, phi + l*NW_,
                                           W1b + (size_t)l*FFN_*NW_,
                                           W2b + (size_t)l*E_*FFN_, tmp);
        add_ln<<<T_/4, 256, 0, stream>>>(h, tmp, g2 + l*E_, b2 + l*E_);
    }

    // pooled mean over seq, then classifier
    pool_partial<<<dim3(16, B_), 256, 0, stream>>>(h, part);
    pool_final<<<B_, 256, 0, stream>>>(part, pooled);
    classify<<<dim3(NC_, B_), 64, 0, stream>>>(pooled, Wc, bc, out);
}